// Round 5
// baseline (300.812 us; speedup 1.0000x reference)
//
#include <hip/hip_runtime.h>

// out[n,o,z,y,x] = b[o] + sum_{kd, d=z+kd-2 in [0,10)} sum_{kh,kw}
//                  x[n,d,y+kh-2,x+kw-2] * W[o,d,kd,kh,kw]
// Diagonal-embed Conv3d == per-z sum of <=5 2D 5x5 convs.
//
// Round-5: WIDEN threads 4 -> 8 output cols (thread grid 16x16, tile
// 16 rows x 128 cols, grid halves to 2560 blocks). Round-4 showed ~57us of
// the 135us dispatch is stall (issue time is only ~78us): per-kh lgkmcnt
// waits and per-plane barriers, phase-aligned across waves. 8-col threads
// feed 400 FMAs from 3 ds_read_b128 (vs 200 from 2) -- every stall point
// amortized 2x. acc[10][8]=80 VGPR -> __launch_bounds__(256,3) so the
// round-1 spill mode is impossible. Accumulation order per output is
// unchanged (d asc, kh asc, kw asc) -> absmax identical.

#define TILE_ROWS 16                      // tile: 16 rows x 128 cols
#define LDS_ROWS  20                      // TILE_ROWS + 4 halo
#define LDS_W     132                     // 128 + 4 halo (528B rows, 16B-aligned)
#define PLANE_W   (LDS_ROWS * LDS_W)      // 2640 words per plane buffer
#define BLOCK     256
#define NSLOT     11                      // ceil(2640/256)
#define SLAB      64                      // floats per (d,kd,kh) weight slab (256B)

typedef const __attribute__((address_space(1))) void gvoid_t;
typedef __attribute__((address_space(3))) void lvoid_t;

// ---- weight repack: W[o][d][kd][kh][kw] (OIDHW) -> Wpk[(d*5+kd)*5+kh][kw*10+o]
__global__ __launch_bounds__(256)
void repack_w_kernel(const float* __restrict__ Wt, float* __restrict__ Wpk)
{
    const int i = blockIdx.x * 256 + threadIdx.x;   // over 10*5*5*5*10 = 12500
    if (i >= 12500) return;
    const int o  = i % 10;
    int t = i / 10;
    const int kw = t % 5; t /= 5;
    const int kh = t % 5; t /= 5;
    const int kd = t % 5;
    const int d  = t / 5;
    const float v = Wt[(((size_t)(o * 10 + d) * 5 + kd) * 5 + kh) * 5 + kw];
    Wpk[(size_t)((d * 5 + kd) * 5 + kh) * SLAB + kw * 10 + o] = v;
}

__global__ __launch_bounds__(BLOCK, 3)
void conv3d_diag_kernel(const float* __restrict__ x,     // [32,10,128,128]
                        const float* __restrict__ Wpk,   // [250][SLAB] repacked
                        const float* __restrict__ bias,  // [10]
                        float* __restrict__ out)         // [32,10,10,128,128]
{
    __shared__ float lds[2 * PLANE_W];    // double-buffered plane tiles (21.1 KB)

    const int tid  = threadIdx.x;
    const int tile = blockIdx.x;          // 0..7   (row tile)
    const int z    = blockIdx.y;          // 0..9   (output depth)
    const int n    = blockIdx.z;          // 0..31  (batch)

    const int y0 = tile * TILE_ROWS;
    const int tx = tid & 15;              // 0..15 -> 8-wide column group
    const int ty = tid >> 4;              // 0..15 -> row within tile
    const int x0 = tx << 3;               // output column base (8 cols/thread)
    const int y  = y0 + ty;               // output row

    // ---- plane-independent staging geometry (computed ONCE) ----
    // slot s stages LDS word e = tid + 256*s from x-plane offset goff[s];
    // goff[s] < 0 marks "no load" (OOB halo / e >= PLANE_W) -> lane masked
    // off the DMA, cell keeps its pre-zeroed value.
    int goff[NSLOT];
    #pragma unroll
    for (int s = 0; s < NSLOT; ++s) {
        const int e  = tid + s * BLOCK;
        const int r  = e / LDS_W;
        const int c  = e - r * LDS_W;
        const int gr = y0 - 2 + r;
        const int gc = c - 2;
        const bool ok = (e < PLANE_W) && ((unsigned)gr < 128u) && ((unsigned)gc < 128u);
        goff[s] = ok ? (gr * 128 + gc) : -1;
    }
    const int lbase = tid & ~63;          // wave-uniform LDS lane base (DMA dest)

    // Pre-zero both buffers: pad cells never touched by the DMA must read 0.
    for (int e = tid; e < 2 * PLANE_W; e += BLOCK) lds[e] = 0.f;

    float acc[10][8];
    #pragma unroll
    for (int o = 0; o < 10; ++o)
        #pragma unroll
        for (int p = 0; p < 8; ++p) acc[o][p] = 0.f;

    const float* xn = x + (size_t)n * (10 * 128 * 128);
    const int d_lo = (z >= 2) ? z - 2 : 0;
    const int d_hi = (z + 2 <= 9) ? z + 2 : 9;

    __syncthreads();                      // zero-fill visible before first DMA

    // ---- prologue: DMA plane d_lo -> buffer 0 ----
    {
        const float* xp = xn + d_lo * (128 * 128);
        #pragma unroll
        for (int s = 0; s < NSLOT; ++s)
            if (goff[s] >= 0)
                __builtin_amdgcn_global_load_lds((gvoid_t*)(xp + goff[s]),
                                                 (lvoid_t*)(lds + s * BLOCK + lbase),
                                                 4, 0, 0);
    }
    __syncthreads();                      // vmcnt drain + barrier: buf0 ready

    int cur = 0;
    #pragma unroll 1
    for (int d = d_lo; d <= d_hi; ++d) {
        // Issue next plane's DMA into the OTHER buffer before computing —
        // its latency hides under this plane's ~2000 FMAs.
        if (d < d_hi) {
            const float* xp = xn + (d + 1) * (128 * 128);
            float* nb = lds + (cur ^ 1) * PLANE_W;
            #pragma unroll
            for (int s = 0; s < NSLOT; ++s)
                if (goff[s] >= 0)
                    __builtin_amdgcn_global_load_lds((gvoid_t*)(xp + goff[s]),
                                                     (lvoid_t*)(nb + s * BLOCK + lbase),
                                                     4, 0, 0);
        }

        const float* bc = lds + cur * PLANE_W;
        const int    kd = d - z + 2;      // in [0,4] by d-range construction
        const float* wbase = Wpk + (size_t)(d * 5 + kd) * 5 * SLAB;

        #pragma unroll 1
        for (int kh = 0; kh < 5; ++kh) {
            // 50 contiguous weights for this (d,kd,kh); uniform 256B-aligned
            // address -> wide s_load into the SGPR file.
            const float* wslab = wbase + kh * SLAB;
            float wv[50];
            #pragma unroll
            for (int j = 0; j < 50; ++j) wv[j] = wslab[j];

            // 12 input floats covering cols x0-2 .. x0+9 (halo offset +2):
            // (ty+kh)*LDS_W + x0 is 16B-aligned (528*row + 32*tx).
            const float* lp = bc + (ty + kh) * LDS_W + x0;
            const float4 r0 = *(const float4*)(lp);
            const float4 r1 = *(const float4*)(lp + 4);
            const float4 r2 = *(const float4*)(lp + 8);
            const float r[12] = {r0.x, r0.y, r0.z, r0.w,
                                 r1.x, r1.y, r1.z, r1.w,
                                 r2.x, r2.y, r2.z, r2.w};

            // Same per-output accumulation order as previous rounds.
            #pragma unroll
            for (int kw = 0; kw < 5; ++kw)
                #pragma unroll
                for (int o = 0; o < 10; ++o)
                    #pragma unroll
                    for (int p = 0; p < 8; ++p)
                        acc[o][p] += r[p + kw] * wv[kw * 10 + o];
        }

        if (d < d_hi) {
            __syncthreads();   // drains next-plane DMA; all reads of bc done
            cur ^= 1;
        }
    }

    // ---- epilogue: bias + 20 coalesced float4 stores ----
    #pragma unroll
    for (int o = 0; o < 10; ++o) {
        const float bo = bias[o];
        const size_t idx = ((((size_t)n * 10 + o) * 10 + z) * 128 + y) * 128 + x0;
        const float4 vlo = make_float4(acc[o][0] + bo, acc[o][1] + bo,
                                       acc[o][2] + bo, acc[o][3] + bo);
        const float4 vhi = make_float4(acc[o][4] + bo, acc[o][5] + bo,
                                       acc[o][6] + bo, acc[o][7] + bo);
        *(float4*)(out + idx)     = vlo;
        *(float4*)(out + idx + 4) = vhi;
    }
}

extern "C" void kernel_launch(void* const* d_in, const int* in_sizes, int n_in,
                              void* d_out, int out_size, void* d_ws, size_t ws_size,
                              hipStream_t stream) {
    const float* x    = (const float*)d_in[0];  // [32,10,128,128]
    const float* Wt   = (const float*)d_in[1];  // [10,10,5,5,5]
    const float* bias = (const float*)d_in[2];  // [10]
    float* out = (float*)d_out;                 // [32,10,10,128,128]
    float* Wpk = (float*)d_ws;                  // 250 * 64 * 4B = 64 KB

    repack_w_kernel<<<dim3((12500 + 255) / 256), 256, 0, stream>>>(Wt, Wpk);

    dim3 grid(8, 10, 32);   // (row tiles, z, n) = 2560 blocks
    conv3d_diag_kernel<<<grid, BLOCK, 0, stream>>>(x, Wpk, bias, out);
}

// Round 6
// 297.385 us; speedup vs baseline: 1.0115x; 1.0115x over previous
//
#include <hip/hip_runtime.h>

// out[n,o,z,y,x] = b[o] + sum_{kd, d=z+kd-2 in [0,10)} sum_{kh,kw}
//                  x[n,d,y+kh-2,x+kw-2] * W[o,d,kd,kh,kw]
// Diagonal-embed Conv3d == per-z sum of <=5 2D 5x5 convs.
//
// Round-6: z-PAIR with SPLIT weight loads. One block computes (z0, z0+1)
// so each staged plane d and each r-read pair feeds TWO z's: plane stages
// per z-pair drop 8.8 -> 5.2, and 2 ds_read_b128 feed 400 FMAs (was 200).
// Round-1's z-pair spill is avoided by never having >50 weight SGPRs live:
// load slab(d,kd0) -> FMA z0 -> load slab(d,kd1) -> FMA z1. Thread width
// stays 4 cols (round-5 showed wave count = stall coverage; don't widen).
// acc[2][10][4]=80 VGPR + ~30 misc < 128 cap at launch_bounds(256,4).
// Per-output accumulation order unchanged (d asc, kh asc, kw asc).

#define TILE_ROWS 8
#define LDS_ROWS  12                      // TILE_ROWS + 4 halo
#define LDS_W     132                     // 128 + 4 halo (528B rows, 16B-aligned)
#define PLANE_W   (LDS_ROWS * LDS_W)      // 1584 words per plane buffer
#define BLOCK     256
#define NSLOT     7                       // ceil(1584/256)
#define SLAB      64                      // floats per (d,kd,kh) weight slab (256B)

typedef const __attribute__((address_space(1))) void gvoid_t;
typedef __attribute__((address_space(3))) void lvoid_t;

// ---- weight repack: W[o][d][kd][kh][kw] (OIDHW) -> Wpk[(d*5+kd)*5+kh][kw*10+o]
__global__ __launch_bounds__(256)
void repack_w_kernel(const float* __restrict__ Wt, float* __restrict__ Wpk)
{
    const int i = blockIdx.x * 256 + threadIdx.x;   // over 10*5*5*5*10 = 12500
    if (i >= 12500) return;
    const int o  = i % 10;
    int t = i / 10;
    const int kw = t % 5; t /= 5;
    const int kh = t % 5; t /= 5;
    const int kd = t % 5;
    const int d  = t / 5;
    const float v = Wt[(((size_t)(o * 10 + d) * 5 + kd) * 5 + kh) * 5 + kw];
    Wpk[(size_t)((d * 5 + kd) * 5 + kh) * SLAB + kw * 10 + o] = v;
}

__global__ __launch_bounds__(BLOCK, 4)
void conv3d_diag_kernel(const float* __restrict__ x,     // [32,10,128,128]
                        const float* __restrict__ Wpk,   // [250][SLAB] repacked
                        const float* __restrict__ bias,  // [10]
                        float* __restrict__ out)         // [32,10,10,128,128]
{
    __shared__ float lds[2 * PLANE_W];    // double-buffered plane tiles (12.7 KB)

    const int tid  = threadIdx.x;
    const int tile = blockIdx.x;          // 0..15  (row tile)
    const int z0   = blockIdx.y << 1;     // 0,2,4,6,8 (z-pair base)
    const int n    = blockIdx.z;          // 0..31  (batch)

    const int y0 = tile * TILE_ROWS;
    const int tx = tid & 31;              // 0..31 -> 4-wide column group
    const int ty = tid >> 5;              // 0..7  -> row within tile
    const int x0 = tx << 2;               // output column base
    const int y  = y0 + ty;               // output row

    // ---- plane-independent staging geometry (computed ONCE) ----
    int goff[NSLOT];
    #pragma unroll
    for (int s = 0; s < NSLOT; ++s) {
        const int e  = tid + s * BLOCK;
        const int r  = e / LDS_W;
        const int c  = e - r * LDS_W;
        const int gr = y0 - 2 + r;
        const int gc = c - 2;
        const bool ok = (e < PLANE_W) && ((unsigned)gr < 128u) && ((unsigned)gc < 128u);
        goff[s] = ok ? (gr * 128 + gc) : -1;
    }
    const int lbase = tid & ~63;          // wave-uniform LDS lane base (DMA dest)

    // Pre-zero both buffers: pad cells never touched by the DMA must read 0.
    for (int e = tid; e < 2 * PLANE_W; e += BLOCK) lds[e] = 0.f;

    float acc[2][10][4];
    #pragma unroll
    for (int zi = 0; zi < 2; ++zi)
        #pragma unroll
        for (int o = 0; o < 10; ++o)
            #pragma unroll
            for (int p = 0; p < 4; ++p) acc[zi][o][p] = 0.f;

    const float* xn = x + (size_t)n * (10 * 128 * 128);
    const int d_lo = (z0 >= 2) ? z0 - 2 : 0;
    const int d_hi = (z0 + 3 <= 9) ? z0 + 3 : 9;

    __syncthreads();                      // zero-fill visible before first DMA

    // ---- prologue: DMA plane d_lo -> buffer 0 ----
    {
        const float* xp = xn + d_lo * (128 * 128);
        #pragma unroll
        for (int s = 0; s < NSLOT; ++s)
            if (goff[s] >= 0)
                __builtin_amdgcn_global_load_lds((gvoid_t*)(xp + goff[s]),
                                                 (lvoid_t*)(lds + s * BLOCK + lbase),
                                                 4, 0, 0);
    }
    __syncthreads();                      // vmcnt drain + barrier: buf0 ready

    int cur = 0;
    #pragma unroll 1
    for (int d = d_lo; d <= d_hi; ++d) {
        // Issue next plane's DMA into the OTHER buffer before computing —
        // its latency hides under this plane's ~2000 FMAs.
        if (d < d_hi) {
            const float* xp = xn + (d + 1) * (128 * 128);
            float* nb = lds + (cur ^ 1) * PLANE_W;
            #pragma unroll
            for (int s = 0; s < NSLOT; ++s)
                if (goff[s] >= 0)
                    __builtin_amdgcn_global_load_lds((gvoid_t*)(xp + goff[s]),
                                                     (lvoid_t*)(nb + s * BLOCK + lbase),
                                                     4, 0, 0);
        }

        const float* bc  = lds + cur * PLANE_W;
        const int    kd0 = d - z0 + 2;    // kd for z0; in [0,5]
        const int    kd1 = kd0 - 1;       // kd for z0+1; in [-1,4]
        const bool   do0 = (kd0 <= 4);    // uniform across block
        const bool   do1 = (kd1 >= 0);    // uniform across block
        const float* wb0 = Wpk + (size_t)(d * 5 + kd0) * 5 * SLAB;
        const float* wb1 = Wpk + (size_t)(d * 5 + kd1) * 5 * SLAB;

        #pragma unroll 1
        for (int kh = 0; kh < 5; ++kh) {
            // 8 input floats covering cols x0-2 .. x0+5 (halo offset +2);
            // shared by BOTH z's: 2 ds_read_b128 feed up to 400 FMAs.
            const float* lp = bc + (ty + kh) * LDS_W + x0;
            const float4 rlo = *(const float4*)(lp);
            const float4 rhi = *(const float4*)(lp + 4);
            const float r[8] = {rlo.x, rlo.y, rlo.z, rlo.w,
                                rhi.x, rhi.y, rhi.z, rhi.w};

            // z0 contribution: 50-weight slab (fits SGPR file), then FMAs.
            if (do0) {
                const float* ws = wb0 + kh * SLAB;
                float wv[50];
                #pragma unroll
                for (int j = 0; j < 50; ++j) wv[j] = ws[j];
                #pragma unroll
                for (int kw = 0; kw < 5; ++kw)
                    #pragma unroll
                    for (int o = 0; o < 10; ++o)
                        #pragma unroll
                        for (int p = 0; p < 4; ++p)
                            acc[0][o][p] += r[p + kw] * wv[kw * 10 + o];
            }
            // z0+1 contribution: second slab loaded AFTER z0's FMAs so at
            // most 50 weight SGPRs are live at once (round-1's spill mode).
            if (do1) {
                const float* ws = wb1 + kh * SLAB;
                float wv[50];
                #pragma unroll
                for (int j = 0; j < 50; ++j) wv[j] = ws[j];
                #pragma unroll
                for (int kw = 0; kw < 5; ++kw)
                    #pragma unroll
                    for (int o = 0; o < 10; ++o)
                        #pragma unroll
                        for (int p = 0; p < 4; ++p)
                            acc[1][o][p] += r[p + kw] * wv[kw * 10 + o];
            }
        }

        if (d < d_hi) {
            __syncthreads();   // drains next-plane DMA; all reads of bc done
            cur ^= 1;
        }
    }

    // ---- epilogue: bias + 20 coalesced float4 stores ----
    #pragma unroll
    for (int zi = 0; zi < 2; ++zi) {
        const int z = z0 + zi;
        #pragma unroll
        for (int o = 0; o < 10; ++o) {
            const float bo = bias[o];
            const float4 v = make_float4(acc[zi][o][0] + bo, acc[zi][o][1] + bo,
                                         acc[zi][o][2] + bo, acc[zi][o][3] + bo);
            const size_t idx = ((((size_t)n * 10 + o) * 10 + z) * 128 + y) * 128 + x0;
            *(float4*)(out + idx) = v;
        }
    }
}

extern "C" void kernel_launch(void* const* d_in, const int* in_sizes, int n_in,
                              void* d_out, int out_size, void* d_ws, size_t ws_size,
                              hipStream_t stream) {
    const float* x    = (const float*)d_in[0];  // [32,10,128,128]
    const float* Wt   = (const float*)d_in[1];  // [10,10,5,5,5]
    const float* bias = (const float*)d_in[2];  // [10]
    float* out = (float*)d_out;                 // [32,10,10,128,128]
    float* Wpk = (float*)d_ws;                  // 250 * 64 * 4B = 64 KB

    repack_w_kernel<<<dim3((12500 + 255) / 256), 256, 0, stream>>>(Wt, Wpk);

    dim3 grid(16, 5, 32);   // (row tiles, z-pairs, n) = 2560 blocks
    conv3d_diag_kernel<<<grid, BLOCK, 0, stream>>>(x, Wpk, bias, out);
}